// Round 1
// baseline (330.053 us; speedup 1.0000x reference)
//
#include <hip/hip_runtime.h>
#include <hip/hip_bf16.h>
#include <math.h>

// Problem constants
#define B_  8
#define S_  128
#define HID_ 256
#define H_  4
#define DH_ 64
#define FF_ 1024
#define M_  (B_ * S_)   // 1024 rows

// ---------------- reductions ----------------
__device__ __forceinline__ float wred_sum(float v) {
#pragma unroll
    for (int o = 32; o >= 1; o >>= 1) v += __shfl_xor(v, o, 64);
    return v;
}
__device__ __forceinline__ float wred_max(float v) {
#pragma unroll
    for (int o = 32; o >= 1; o >>= 1) v = fmaxf(v, __shfl_xor(v, o, 64));
    return v;
}

// block of 128 threads (2 waves)
__device__ __forceinline__ float block_sum_128(float v, float* s2, int tid) {
    v = wred_sum(v);
    __syncthreads();                 // protect s2 from previous use
    if ((tid & 63) == 0) s2[tid >> 6] = v;
    __syncthreads();
    return s2[0] + s2[1];
}
__device__ __forceinline__ float block_max_128(float v, float* s2, int tid) {
    v = wred_max(v);
    __syncthreads();
    if ((tid & 63) == 0) s2[tid >> 6] = v;
    __syncthreads();
    return fmaxf(s2[0], s2[1]);
}
// softmax across the 128 threads of the block; each thread holds one logit
__device__ __forceinline__ float softmax128(float logit, float* s2, int tid) {
    float m = block_max_128(logit, s2, tid);
    float e = expf(logit - m);
    float s = block_sum_128(e, s2, tid);
    return e / s;
}

// block of 256 threads (4 waves)
__device__ __forceinline__ float block_sum_256(float v, float* s4, int tid) {
    v = wred_sum(v);
    __syncthreads();
    if ((tid & 63) == 0) s4[tid >> 6] = v;
    __syncthreads();
    return s4[0] + s4[1] + s4[2] + s4[3];
}

// ---------------- kernel 1: q,k,v = x@W + b ----------------
// grid (3, M/8), block 256.  blockIdx.x selects which GEMM.
__global__ __launch_bounds__(256) void qkv_kernel(
    const float* __restrict__ x,
    const float* __restrict__ Wq, const float* __restrict__ bq,
    const float* __restrict__ Wk, const float* __restrict__ bk,
    const float* __restrict__ Wv, const float* __restrict__ bv,
    float* __restrict__ q, float* __restrict__ k, float* __restrict__ v)
{
    __shared__ float xs[8 * HID_];
    const float* W; const float* bias; float* out;
    if (blockIdx.x == 0)      { W = Wq; bias = bq; out = q; }
    else if (blockIdx.x == 1) { W = Wk; bias = bk; out = k; }
    else                      { W = Wv; bias = bv; out = v; }
    int m0 = blockIdx.y * 8;
    int tid = threadIdx.x;
    for (int idx = tid; idx < 8 * HID_; idx += 256)
        xs[idx] = x[m0 * HID_ + idx];
    __syncthreads();
    int n = tid;
    float acc[8] = {0.f,0.f,0.f,0.f,0.f,0.f,0.f,0.f};
#pragma unroll 4
    for (int kk = 0; kk < HID_; ++kk) {
        float w = W[kk * HID_ + n];
#pragma unroll
        for (int r = 0; r < 8; ++r) acc[r] = fmaf(xs[r * HID_ + kk], w, acc[r]);
    }
    float bn = bias[n];
#pragma unroll
    for (int r = 0; r < 8; ++r) out[(m0 + r) * HID_ + n] = acc[r] + bn;
}

// ---------------- kernel 2: aq = q@AWq+Abq ; ak = k@AWk+Abk ----------------
__global__ __launch_bounds__(256) void aqk_kernel(
    const float* __restrict__ q, const float* __restrict__ k,
    const float* __restrict__ AWq, const float* __restrict__ Abq,
    const float* __restrict__ AWk, const float* __restrict__ Abk,
    float* __restrict__ aq, float* __restrict__ ak)
{
    __shared__ float xs[8 * HID_];
    const float* in; const float* W; const float* bias; float* out;
    if (blockIdx.x == 0) { in = q; W = AWq; bias = Abq; out = aq; }
    else                 { in = k; W = AWk; bias = Abk; out = ak; }
    int m0 = blockIdx.y * 8;
    int tid = threadIdx.x;
    for (int idx = tid; idx < 8 * HID_; idx += 256)
        xs[idx] = in[m0 * HID_ + idx];
    __syncthreads();
    int n = tid;
    float acc[8] = {0.f,0.f,0.f,0.f,0.f,0.f,0.f,0.f};
#pragma unroll 4
    for (int kk = 0; kk < HID_; ++kk) {
        float w = W[kk * HID_ + n];
#pragma unroll
        for (int r = 0; r < 8; ++r) acc[r] = fmaf(xs[r * HID_ + kk], w, acc[r]);
    }
    float bn = bias[n];
#pragma unroll
    for (int r = 0; r < 8; ++r) out[(m0 + r) * HID_ + n] = acc[r] + bn;
}

// ---------------- kernel 3: attention ----------------
// grid = B*H*S blocks, 128 threads (one per key j); one block per (b,h,i)
__global__ __launch_bounds__(128) void attn_kernel(
    const float* __restrict__ q, const float* __restrict__ k, const float* __restrict__ v,
    const float* __restrict__ aq, const float* __restrict__ ak,
    const float* __restrict__ mask,
    const float* __restrict__ order_w, const float* __restrict__ order_b_p,
    const float* __restrict__ dist_w,  const float* __restrict__ dist_b_p,
    const float* __restrict__ scalar_p,
    float* __restrict__ ctx)
{
    __shared__ float sq[DH_], saq[DH_], sow1[DH_], sow2[DH_], sdw1[DH_], sdw2[DH_];
    __shared__ float fp[S_];
    __shared__ float part[S_];
    __shared__ float s2[2];

    int tid = threadIdx.x;
    int bid = blockIdx.x;
    int b = bid >> 9;          // / (H*S) = /512
    int h = (bid >> 7) & 3;    // / S % H
    int i = bid & 127;         // % S
    int qoff = (b * S_ + i) * HID_ + h * DH_;

    if (tid < 64) {
        sq[tid]  = q[qoff + tid];
        saq[tid] = aq[qoff + tid];
    } else {
        int t = tid - 64;
        sow1[t] = order_w[t];       sow2[t] = order_w[64 + t];
        sdw1[t] = dist_w[t];        sdw2[t] = dist_w[64 + t];
    }
    __syncthreads();

    int j = tid;
    const float4* k4 = (const float4*)(k  + (size_t)(b * S_ + j) * HID_ + h * DH_);
    const float4* a4 = (const float4*)(ak + (size_t)(b * S_ + j) * HID_ + h * DH_);
    float sc_ = 0.f, as_ = 0.f, ko = 0.f, kd = 0.f, qo = 0.f, qd = 0.f;
#pragma unroll
    for (int d4 = 0; d4 < DH_ / 4; ++d4) {
        float4 kv = k4[d4];
        float4 av = a4[d4];
#pragma unroll
        for (int u = 0; u < 4; ++u) {
            int d = d4 * 4 + u;
            float kvf = (&kv.x)[u];
            float avf = (&av.x)[u];
            float qvf = sq[d];
            sc_ = fmaf(qvf, kvf, sc_);
            ko  = fmaf(sow2[d], kvf, ko);
            kd  = fmaf(sdw2[d], kvf, kd);
            qo  = fmaf(qvf, sow1[d], qo);
            qd  = fmaf(qvf, sdw1[d], qd);
            as_ = fmaf(saq[d], avf, as_);
        }
    }
    float mval = mask[(b * S_ + i) * S_ + j];
    float scal = scalar_p[0];
    float sc2 = scal * scal;
    float x_o = qo + ko + order_b_p[0];
    float pr_o = 1.f / (1.f + expf(-x_o));
    float err_o = (j > i) ? logf(pr_o + 1e-24f) : logf(1.f - pr_o + 1e-24f);
    int dj = j - i; if (dj < 0) dj = -dj;
    float gd = logf((float)dj + 1.f);
    float pd = qd + kd + dist_b_p[0];
    float ddv = gd - pd;
    float err_d = -0.5f * ddv * ddv * sc2;
    float rich = sc_ + err_o + err_d;

    const float inv = 0.125f;  // 1/sqrt(DH)
    float p0 = softmax128(sc_  * inv + mval, s2, tid);   // origin_probs
    float p1 = softmax128(rich * inv + mval, s2, tid);   // rich_probs
    float pc = softmax128(p0 + 0.5f * p1,    s2, tid);   // combined
    float pa = softmax128(as_  * inv + mval, s2, tid);   // attack_probs
    float pf = softmax128(pc + 0.5f * pa,    s2, tid);   // final_probs

    fp[j] = pf;
    __syncthreads();

    // ctx row: both waves split the key range; d = tid&63
    int d = tid & 63;
    int j0 = tid & 64;                 // 0 or 64
    const float* vbase = v + (size_t)b * S_ * HID_ + h * DH_ + d;
    float accv = 0.f;
#pragma unroll 8
    for (int jj = j0; jj < j0 + 64; ++jj)
        accv = fmaf(fp[jj], vbase[(size_t)jj * HID_], accv);
    part[tid] = accv;
    __syncthreads();
    if (tid < 64)
        ctx[qoff + tid] = part[tid] + part[tid + 64];
}

// ---------------- kernel 4: h = LN(ctx@Wd + bd + x) ----------------
// grid M/4 blocks, 256 threads
__global__ __launch_bounds__(256) void dense_ln1_kernel(
    const float* __restrict__ ctx, const float* __restrict__ Wd, const float* __restrict__ bd,
    const float* __restrict__ x, const float* __restrict__ g1, const float* __restrict__ beta1,
    float* __restrict__ hout)
{
    __shared__ float cs[4 * HID_];
    __shared__ float s4[4];
    int m0 = blockIdx.x * 4;
    int tid = threadIdx.x;
    for (int idx = tid; idx < 4 * HID_; idx += 256)
        cs[idx] = ctx[m0 * HID_ + idx];
    __syncthreads();
    int n = tid;
    float acc[4] = {0.f,0.f,0.f,0.f};
#pragma unroll 4
    for (int kk = 0; kk < HID_; ++kk) {
        float w = Wd[kk * HID_ + n];
#pragma unroll
        for (int r = 0; r < 4; ++r) acc[r] = fmaf(cs[r * HID_ + kk], w, acc[r]);
    }
    float bdn = bd[n], gn = g1[n], bn = beta1[n];
#pragma unroll
    for (int r = 0; r < 4; ++r) {
        float val = acc[r] + bdn + x[(m0 + r) * HID_ + n];
        float mean = block_sum_256(val, s4, tid) * (1.f / HID_);
        float dv = val - mean;
        float var = block_sum_256(dv * dv, s4, tid) * (1.f / HID_);
        hout[(m0 + r) * HID_ + n] = dv * rsqrtf(var + 1e-12f) * gn + bn;
    }
}

// ---------------- kernel 5: f1 = gelu(h@W1 + b1) ----------------
// grid (FF/256, M/8), block 256
__global__ __launch_bounds__(256) void ff1_kernel(
    const float* __restrict__ h, const float* __restrict__ W1, const float* __restrict__ b1,
    float* __restrict__ f1)
{
    __shared__ float hs[8 * HID_];
    int m0 = blockIdx.y * 8;
    int n = blockIdx.x * 256 + threadIdx.x;
    for (int idx = threadIdx.x; idx < 8 * HID_; idx += 256)
        hs[idx] = h[m0 * HID_ + idx];
    __syncthreads();
    float acc[8] = {0.f,0.f,0.f,0.f,0.f,0.f,0.f,0.f};
#pragma unroll 4
    for (int kk = 0; kk < HID_; ++kk) {
        float w = W1[kk * FF_ + n];
#pragma unroll
        for (int r = 0; r < 8; ++r) acc[r] = fmaf(hs[r * HID_ + kk], w, acc[r]);
    }
    float bn = b1[n];
#pragma unroll
    for (int r = 0; r < 8; ++r) {
        float vv = acc[r] + bn;
        f1[(m0 + r) * FF_ + n] = 0.5f * vv * (1.f + erff(vv * 0.70710678118654752f));
    }
}

// ---------------- kernel 6: out = LN(f1@W2 + b2 + h) ----------------
// grid M/4 blocks, 256 threads
__global__ __launch_bounds__(256) void ff2_ln2_kernel(
    const float* __restrict__ f1, const float* __restrict__ W2, const float* __restrict__ b2,
    const float* __restrict__ h, const float* __restrict__ g2, const float* __restrict__ beta2,
    float* __restrict__ out)
{
    __shared__ float fs[4 * FF_];
    __shared__ float s4[4];
    int m0 = blockIdx.x * 4;
    int tid = threadIdx.x;
    for (int idx = tid; idx < 4 * FF_; idx += 256)
        fs[idx] = f1[m0 * FF_ + idx];
    __syncthreads();
    int n = tid;
    float acc[4] = {0.f,0.f,0.f,0.f};
#pragma unroll 4
    for (int kk = 0; kk < FF_; ++kk) {
        float w = W2[kk * HID_ + n];
#pragma unroll
        for (int r = 0; r < 4; ++r) acc[r] = fmaf(fs[r * FF_ + kk], w, acc[r]);
    }
    float bn2 = b2[n], gn = g2[n], bn = beta2[n];
#pragma unroll
    for (int r = 0; r < 4; ++r) {
        float val = acc[r] + bn2 + h[(m0 + r) * HID_ + n];
        float mean = block_sum_256(val, s4, tid) * (1.f / HID_);
        float dv = val - mean;
        float var = block_sum_256(dv * dv, s4, tid) * (1.f / HID_);
        out[(m0 + r) * HID_ + n] = dv * rsqrtf(var + 1e-12f) * gn + bn;
    }
}

// ---------------- launch ----------------
extern "C" void kernel_launch(void* const* d_in, const int* in_sizes, int n_in,
                              void* d_out, int out_size, void* d_ws, size_t ws_size,
                              hipStream_t stream) {
    const float* x        = (const float*)d_in[0];
    const float* mask     = (const float*)d_in[1];
    const float* Wq       = (const float*)d_in[2];
    const float* bq       = (const float*)d_in[3];
    const float* Wk       = (const float*)d_in[4];
    const float* bk       = (const float*)d_in[5];
    const float* Wv       = (const float*)d_in[6];
    const float* bv       = (const float*)d_in[7];
    const float* order_w  = (const float*)d_in[8];
    const float* order_b  = (const float*)d_in[9];
    const float* dist_w   = (const float*)d_in[10];
    const float* dist_b   = (const float*)d_in[11];
    const float* scalar   = (const float*)d_in[12];
    const float* AWq      = (const float*)d_in[13];
    const float* Abq      = (const float*)d_in[14];
    const float* AWk      = (const float*)d_in[15];
    const float* Abk      = (const float*)d_in[16];
    const float* Wd       = (const float*)d_in[17];
    const float* bd       = (const float*)d_in[18];
    const float* g1       = (const float*)d_in[19];
    const float* beta1    = (const float*)d_in[20];
    const float* W1       = (const float*)d_in[21];
    const float* b1       = (const float*)d_in[22];
    const float* W2       = (const float*)d_in[23];
    const float* b2       = (const float*)d_in[24];
    const float* g2       = (const float*)d_in[25];
    const float* beta2    = (const float*)d_in[26];

    const size_t T = (size_t)M_ * HID_;     // 262144 floats per activation buffer
    float* ws   = (float*)d_ws;
    float* qb   = ws;
    float* kb   = ws + 1 * T;
    float* vb   = ws + 2 * T;
    float* aqb  = ws + 3 * T;
    float* akb  = ws + 4 * T;
    float* ctxb = ws + 5 * T;
    float* hb   = ws + 6 * T;
    float* f1b  = ws + 7 * T;               // size M_*FF_ = 4*T

    qkv_kernel<<<dim3(3, M_ / 8), 256, 0, stream>>>(x, Wq, bq, Wk, bk, Wv, bv, qb, kb, vb);
    aqk_kernel<<<dim3(2, M_ / 8), 256, 0, stream>>>(qb, kb, AWq, Abq, AWk, Abk, aqb, akb);
    attn_kernel<<<B_ * H_ * S_, 128, 0, stream>>>(qb, kb, vb, aqb, akb, mask,
                                                  order_w, order_b, dist_w, dist_b, scalar, ctxb);
    dense_ln1_kernel<<<M_ / 4, 256, 0, stream>>>(ctxb, Wd, bd, x, g1, beta1, hb);
    ff1_kernel<<<dim3(FF_ / 256, M_ / 8), 256, 0, stream>>>(hb, W1, b1, f1b);
    ff2_ln2_kernel<<<M_ / 4, 256, 0, stream>>>(f1b, W2, b2, hb, g2, beta2, (float*)d_out);
}

// Round 2
// 236.082 us; speedup vs baseline: 1.3980x; 1.3980x over previous
//
#include <hip/hip_runtime.h>
#include <hip/hip_bf16.h>
#include <math.h>

// Problem constants
#define B_  8
#define S_  128
#define HID_ 256
#define H_  4
#define DH_ 64
#define FF_ 1024
#define M_  (B_ * S_)   // 1024 rows

#define BM 64
#define BN 64
#define BK 32

enum { EP_STORE = 0, EP_BIAS = 1, EP_GELU = 2 };

// ---------------- reductions ----------------
__device__ __forceinline__ float wred_sum(float v) {
#pragma unroll
    for (int o = 32; o >= 1; o >>= 1) v += __shfl_xor(v, o, 64);
    return v;
}
__device__ __forceinline__ float wred_max(float v) {
#pragma unroll
    for (int o = 32; o >= 1; o >>= 1) v = fmaxf(v, __shfl_xor(v, o, 64));
    return v;
}
__device__ __forceinline__ float block_sum_128(float v, float* s2, int tid) {
    v = wred_sum(v);
    __syncthreads();
    if ((tid & 63) == 0) s2[tid >> 6] = v;
    __syncthreads();
    return s2[0] + s2[1];
}
__device__ __forceinline__ float block_max_128(float v, float* s2, int tid) {
    v = wred_max(v);
    __syncthreads();
    if ((tid & 63) == 0) s2[tid >> 6] = v;
    __syncthreads();
    return fmaxf(s2[0], s2[1]);
}
__device__ __forceinline__ float softmax128(float logit, float* s2, int tid) {
    float m = block_max_128(logit, s2, tid);
    float e = expf(logit - m);
    float s = block_sum_128(e, s2, tid);
    return e / s;
}
__device__ __forceinline__ float block_sum_256(float v, float* s4, int tid) {
    v = wred_sum(v);
    __syncthreads();
    if ((tid & 63) == 0) s4[tid >> 6] = v;
    __syncthreads();
    return s4[0] + s4[1] + s4[2] + s4[3];
}

// ---------------- tiled GEMM core ----------------
// C[M,N] (+= is external) = A[:, k0:k0+kLen] @ W[k0:k0+kLen, :]  for this block's
// 64x64 tile.  256 threads, 4x4 micro-tile, double-buffered LDS.
template<int EPI>
__device__ __forceinline__ void gemm_core(
    const float* __restrict__ A, const float* __restrict__ W,
    const float* __restrict__ bias, float* __restrict__ C,
    int N, int ldA, int k0, int kLen)
{
    __shared__ float As[2][BK][BM + 4];   // +4 pad keeps float4 alignment (68*4B=272B, 16B-mult)
    __shared__ float Ws[2][BK][BN];

    const int tid = threadIdx.x;
    const int tx = tid & 15, ty = tid >> 4;
    const int m0 = blockIdx.y * BM;
    const int n0 = blockIdx.x * BN;

    // A staging: 64 rows x 32 cols; thread loads 8 contiguous floats (2 float4)
    const int a_row = tid >> 2;           // 0..63
    const int a_col = (tid & 3) << 3;     // 0,8,16,24
    const float* Aptr = A + (size_t)(m0 + a_row) * ldA + k0 + a_col;
    // W staging: 32 rows x 64 cols; thread loads 8 contiguous floats
    const int w_row = tid >> 3;           // 0..31
    const int w_col = (tid & 7) << 3;     // 0,8,...,56
    const float* Wptr = W + (size_t)(k0 + w_row) * N + n0 + w_col;

    float4 ra0, ra1, rw0, rw1;
    auto fetch = [&](int t) {
        const float* ap = Aptr + t * BK;
        ra0 = *(const float4*)(ap);
        ra1 = *(const float4*)(ap + 4);
        const float* wp = Wptr + (size_t)t * BK * N;
        rw0 = *(const float4*)(wp);
        rw1 = *(const float4*)(wp + 4);
    };
    auto commit = [&](int buf) {
        As[buf][a_col + 0][a_row] = ra0.x;
        As[buf][a_col + 1][a_row] = ra0.y;
        As[buf][a_col + 2][a_row] = ra0.z;
        As[buf][a_col + 3][a_row] = ra0.w;
        As[buf][a_col + 4][a_row] = ra1.x;
        As[buf][a_col + 5][a_row] = ra1.y;
        As[buf][a_col + 6][a_row] = ra1.z;
        As[buf][a_col + 7][a_row] = ra1.w;
        *(float4*)&Ws[buf][w_row][w_col]     = rw0;
        *(float4*)&Ws[buf][w_row][w_col + 4] = rw1;
    };

    float acc[4][4] = {};
    const int ktiles = kLen >> 5;

    fetch(0);
    commit(0);
    __syncthreads();
    for (int t = 0; t < ktiles; ++t) {
        const bool more = (t + 1 < ktiles);
        if (more) fetch(t + 1);
        const int buf = t & 1;
#pragma unroll
        for (int kk = 0; kk < BK; ++kk) {
            float4 a = *(const float4*)&As[buf][kk][ty << 2];
            float4 w = *(const float4*)&Ws[buf][kk][tx << 2];
            acc[0][0] = fmaf(a.x, w.x, acc[0][0]);
            acc[0][1] = fmaf(a.x, w.y, acc[0][1]);
            acc[0][2] = fmaf(a.x, w.z, acc[0][2]);
            acc[0][3] = fmaf(a.x, w.w, acc[0][3]);
            acc[1][0] = fmaf(a.y, w.x, acc[1][0]);
            acc[1][1] = fmaf(a.y, w.y, acc[1][1]);
            acc[1][2] = fmaf(a.y, w.z, acc[1][2]);
            acc[1][3] = fmaf(a.y, w.w, acc[1][3]);
            acc[2][0] = fmaf(a.z, w.x, acc[2][0]);
            acc[2][1] = fmaf(a.z, w.y, acc[2][1]);
            acc[2][2] = fmaf(a.z, w.z, acc[2][2]);
            acc[2][3] = fmaf(a.z, w.w, acc[2][3]);
            acc[3][0] = fmaf(a.w, w.x, acc[3][0]);
            acc[3][1] = fmaf(a.w, w.y, acc[3][1]);
            acc[3][2] = fmaf(a.w, w.z, acc[3][2]);
            acc[3][3] = fmaf(a.w, w.w, acc[3][3]);
        }
        __syncthreads();
        if (more) {
            commit((t + 1) & 1);
            __syncthreads();
        }
    }

    const int row = m0 + (ty << 2);
    const int col = n0 + (tx << 2);
    float4 bv = make_float4(0.f, 0.f, 0.f, 0.f);
    if (EPI != EP_STORE) bv = *(const float4*)&bias[col];
#pragma unroll
    for (int r = 0; r < 4; ++r) {
        float4 o;
        o.x = acc[r][0] + bv.x;
        o.y = acc[r][1] + bv.y;
        o.z = acc[r][2] + bv.z;
        o.w = acc[r][3] + bv.w;
        if (EPI == EP_GELU) {
            o.x = 0.5f * o.x * (1.f + erff(o.x * 0.70710678118654752f));
            o.y = 0.5f * o.y * (1.f + erff(o.y * 0.70710678118654752f));
            o.z = 0.5f * o.z * (1.f + erff(o.z * 0.70710678118654752f));
            o.w = 0.5f * o.w * (1.f + erff(o.w * 0.70710678118654752f));
        }
        *(float4*)&C[(size_t)(row + r) * N + col] = o;
    }
}

// ---------------- GEMM wrappers ----------------
__global__ __launch_bounds__(256) void qkv_gemm(
    const float* __restrict__ x,
    const float* __restrict__ Wq, const float* __restrict__ bq,
    const float* __restrict__ Wk, const float* __restrict__ bk,
    const float* __restrict__ Wv, const float* __restrict__ bv,
    float* __restrict__ q, float* __restrict__ k, float* __restrict__ v)
{
    const float* W; const float* b; float* out;
    if (blockIdx.z == 0)      { W = Wq; b = bq; out = q; }
    else if (blockIdx.z == 1) { W = Wk; b = bk; out = k; }
    else                      { W = Wv; b = bv; out = v; }
    gemm_core<EP_BIAS>(x, W, b, out, HID_, HID_, 0, HID_);
}

__global__ __launch_bounds__(256) void aqk_gemm(
    const float* __restrict__ q, const float* __restrict__ k,
    const float* __restrict__ AWq, const float* __restrict__ Abq,
    const float* __restrict__ AWk, const float* __restrict__ Abk,
    float* __restrict__ aq, float* __restrict__ ak)
{
    const float* A; const float* W; const float* b; float* out;
    if (blockIdx.z == 0) { A = q; W = AWq; b = Abq; out = aq; }
    else                 { A = k; W = AWk; b = Abk; out = ak; }
    gemm_core<EP_BIAS>(A, W, b, out, HID_, HID_, 0, HID_);
}

__global__ __launch_bounds__(256) void dense_gemm(
    const float* __restrict__ ctx, const float* __restrict__ Wd,
    float* __restrict__ pd)   // 2 partials, contiguous
{
    const int z = blockIdx.z;       // split-K 2, 128 each
    gemm_core<EP_STORE>(ctx, Wd, nullptr, pd + (size_t)z * M_ * HID_, HID_, HID_, z * 128, 128);
}

__global__ __launch_bounds__(256) void ff1_gemm(
    const float* __restrict__ h, const float* __restrict__ W1, const float* __restrict__ b1,
    float* __restrict__ f1)
{
    gemm_core<EP_GELU>(h, W1, b1, f1, FF_, HID_, 0, HID_);
}

__global__ __launch_bounds__(256) void ff2_gemm(
    const float* __restrict__ f1, const float* __restrict__ W2,
    float* __restrict__ p0, float* __restrict__ p1,
    float* __restrict__ p2, float* __restrict__ p3)
{
    const int z = blockIdx.z;       // split-K 4, 256 each
    float* C = (z == 0) ? p0 : (z == 1) ? p1 : (z == 2) ? p2 : p3;
    gemm_core<EP_STORE>(f1, W2, nullptr, C, HID_, FF_, z * 256, 256);
}

// ---------------- attention ----------------
// grid = B*H*S blocks, 128 threads (one per key j)
__global__ __launch_bounds__(128) void attn_kernel(
    const float* __restrict__ q, const float* __restrict__ k, const float* __restrict__ v,
    const float* __restrict__ aq, const float* __restrict__ ak,
    const float* __restrict__ mask,
    const float* __restrict__ order_w, const float* __restrict__ order_b_p,
    const float* __restrict__ dist_w,  const float* __restrict__ dist_b_p,
    const float* __restrict__ scalar_p,
    float* __restrict__ ctx)
{
    __shared__ float sq[DH_], saq[DH_], sow1[DH_], sow2[DH_], sdw1[DH_], sdw2[DH_];
    __shared__ float fp[S_];
    __shared__ float part[S_];
    __shared__ float s2[2];

    int tid = threadIdx.x;
    int bid = blockIdx.x;
    int b = bid >> 9;
    int h = (bid >> 7) & 3;
    int i = bid & 127;
    int qoff = (b * S_ + i) * HID_ + h * DH_;

    if (tid < 64) {
        sq[tid]  = q[qoff + tid];
        saq[tid] = aq[qoff + tid];
    } else {
        int t = tid - 64;
        sow1[t] = order_w[t];       sow2[t] = order_w[64 + t];
        sdw1[t] = dist_w[t];        sdw2[t] = dist_w[64 + t];
    }
    __syncthreads();

    int j = tid;
    const float4* k4 = (const float4*)(k  + (size_t)(b * S_ + j) * HID_ + h * DH_);
    const float4* a4 = (const float4*)(ak + (size_t)(b * S_ + j) * HID_ + h * DH_);
    float sc_ = 0.f, as_ = 0.f, ko = 0.f, kd = 0.f, qo = 0.f, qd = 0.f;
#pragma unroll
    for (int d4 = 0; d4 < DH_ / 4; ++d4) {
        float4 kv = k4[d4];
        float4 av = a4[d4];
#pragma unroll
        for (int u = 0; u < 4; ++u) {
            int d = d4 * 4 + u;
            float kvf = (&kv.x)[u];
            float avf = (&av.x)[u];
            float qvf = sq[d];
            sc_ = fmaf(qvf, kvf, sc_);
            ko  = fmaf(sow2[d], kvf, ko);
            kd  = fmaf(sdw2[d], kvf, kd);
            qo  = fmaf(qvf, sow1[d], qo);
            qd  = fmaf(qvf, sdw1[d], qd);
            as_ = fmaf(saq[d], avf, as_);
        }
    }
    float mval = mask[(b * S_ + i) * S_ + j];
    float scal = scalar_p[0];
    float sc2 = scal * scal;
    float x_o = qo + ko + order_b_p[0];
    float pr_o = 1.f / (1.f + expf(-x_o));
    float err_o = (j > i) ? logf(pr_o + 1e-24f) : logf(1.f - pr_o + 1e-24f);
    int dj = j - i; if (dj < 0) dj = -dj;
    float gd = logf((float)dj + 1.f);
    float pd = qd + kd + dist_b_p[0];
    float ddv = gd - pd;
    float err_d = -0.5f * ddv * ddv * sc2;
    float rich = sc_ + err_o + err_d;

    const float inv = 0.125f;
    float p0 = softmax128(sc_  * inv + mval, s2, tid);
    float p1 = softmax128(rich * inv + mval, s2, tid);
    float pc = softmax128(p0 + 0.5f * p1,    s2, tid);
    float pa = softmax128(as_  * inv + mval, s2, tid);
    float pf = softmax128(pc + 0.5f * pa,    s2, tid);

    fp[j] = pf;
    __syncthreads();

    int d = tid & 63;
    int j0 = tid & 64;
    const float* vbase = v + (size_t)b * S_ * HID_ + h * DH_ + d;
    float accv = 0.f;
#pragma unroll 8
    for (int jj = j0; jj < j0 + 64; ++jj)
        accv = fmaf(fp[jj], vbase[(size_t)jj * HID_], accv);
    part[tid] = accv;
    __syncthreads();
    if (tid < 64)
        ctx[qoff + tid] = part[tid] + part[tid + 64];
}

// ---------------- LN kernels (reduce split-K partials + bias + residual + LN) --------
__global__ __launch_bounds__(256) void ln1_kernel(
    const float* __restrict__ pd,   // 2 partials contiguous
    const float* __restrict__ bd, const float* __restrict__ x,
    const float* __restrict__ g1, const float* __restrict__ beta1,
    float* __restrict__ h)
{
    __shared__ float s4[4];
    const int row = blockIdx.x;
    const int n = threadIdx.x;
    const size_t idx = (size_t)row * HID_ + n;
    float val = pd[idx] + pd[(size_t)M_ * HID_ + idx] + bd[n] + x[idx];
    float mean = block_sum_256(val, s4, n) * (1.f / HID_);
    float dv = val - mean;
    float var = block_sum_256(dv * dv, s4, n) * (1.f / HID_);
    h[idx] = dv * rsqrtf(var + 1e-12f) * g1[n] + beta1[n];
}

__global__ __launch_bounds__(256) void ln2_kernel(
    const float* __restrict__ p0, const float* __restrict__ p1,
    const float* __restrict__ p2, const float* __restrict__ p3,
    const float* __restrict__ b2, const float* __restrict__ h,
    const float* __restrict__ g2, const float* __restrict__ beta2,
    float* __restrict__ out)
{
    __shared__ float s4[4];
    const int row = blockIdx.x;
    const int n = threadIdx.x;
    const size_t idx = (size_t)row * HID_ + n;
    float val = p0[idx] + p1[idx] + p2[idx] + p3[idx] + b2[n] + h[idx];
    float mean = block_sum_256(val, s4, n) * (1.f / HID_);
    float dv = val - mean;
    float var = block_sum_256(dv * dv, s4, n) * (1.f / HID_);
    out[idx] = dv * rsqrtf(var + 1e-12f) * g2[n] + beta2[n];
}

// ---------------- launch ----------------
extern "C" void kernel_launch(void* const* d_in, const int* in_sizes, int n_in,
                              void* d_out, int out_size, void* d_ws, size_t ws_size,
                              hipStream_t stream) {
    const float* x        = (const float*)d_in[0];
    const float* mask     = (const float*)d_in[1];
    const float* Wq       = (const float*)d_in[2];
    const float* bq       = (const float*)d_in[3];
    const float* Wk       = (const float*)d_in[4];
    const float* bk       = (const float*)d_in[5];
    const float* Wv       = (const float*)d_in[6];
    const float* bv       = (const float*)d_in[7];
    const float* order_w  = (const float*)d_in[8];
    const float* order_b  = (const float*)d_in[9];
    const float* dist_w   = (const float*)d_in[10];
    const float* dist_b   = (const float*)d_in[11];
    const float* scalar   = (const float*)d_in[12];
    const float* AWq      = (const float*)d_in[13];
    const float* Abq      = (const float*)d_in[14];
    const float* AWk      = (const float*)d_in[15];
    const float* Abk      = (const float*)d_in[16];
    const float* Wd       = (const float*)d_in[17];
    const float* bd       = (const float*)d_in[18];
    const float* g1       = (const float*)d_in[19];
    const float* beta1    = (const float*)d_in[20];
    const float* W1       = (const float*)d_in[21];
    const float* b1       = (const float*)d_in[22];
    const float* W2       = (const float*)d_in[23];
    const float* b2       = (const float*)d_in[24];
    const float* g2       = (const float*)d_in[25];
    const float* beta2    = (const float*)d_in[26];

    const size_t T = (size_t)M_ * HID_;   // 1 MB each
    float* ws   = (float*)d_ws;
    // liveness-packed layout (11 slots):
    float* qb   = ws + 0 * T;   // dead after attn -> pf0
    float* kb   = ws + 1 * T;   // dead after attn -> pf1
    float* vb   = ws + 2 * T;   // dead after attn -> hb
    float* aqb  = ws + 3 * T;   // dead after attn -> f1b[0]
    float* akb  = ws + 4 * T;   // dead after attn -> f1b[1]
    float* ctxb = ws + 5 * T;   // dead after dense -> f1b[2]
    float* pdb  = ws + 7 * T;   // 2T: slots 7,8
    float* hb   = ws + 2 * T;
    float* f1b  = ws + 3 * T;   // 4T: slots 3,4,5,6
    float* pf0  = ws + 0 * T;
    float* pf1  = ws + 1 * T;
    float* pf2  = ws + 9 * T;
    float* pf3  = ws + 10 * T;

    qkv_gemm<<<dim3(4, 16, 3), 256, 0, stream>>>(x, Wq, bq, Wk, bk, Wv, bv, qb, kb, vb);
    aqk_gemm<<<dim3(4, 16, 2), 256, 0, stream>>>(qb, kb, AWq, Abq, AWk, Abk, aqb, akb);
    attn_kernel<<<B_ * H_ * S_, 128, 0, stream>>>(qb, kb, vb, aqb, akb, mask,
                                                  order_w, order_b, dist_w, dist_b, scalar, ctxb);
    dense_gemm<<<dim3(4, 16, 2), 256, 0, stream>>>(ctxb, Wd, pdb);
    ln1_kernel<<<M_, 256, 0, stream>>>(pdb, bd, x, g1, beta1, hb);
    ff1_gemm<<<dim3(16, 16, 1), 256, 0, stream>>>(hb, W1, b1, f1b);
    ff2_gemm<<<dim3(4, 16, 4), 256, 0, stream>>>(f1b, W2, pf0, pf1, pf2, pf3);
    ln2_kernel<<<M_, 256, 0, stream>>>(pf0, pf1, pf2, pf3, b2, hb, g2, beta2, (float*)d_out);
}

// Round 3
// 200.622 us; speedup vs baseline: 1.6451x; 1.1767x over previous
//
#include <hip/hip_runtime.h>
#include <hip/hip_bf16.h>
#include <math.h>

// Problem constants
#define B_  8
#define S_  128
#define HID_ 256
#define H_  4
#define DH_ 64
#define FF_ 1024
#define M_  (B_ * S_)   // 1024 rows

#define BM 64
#define BN 64
#define BK 32

enum { EP_STORE = 0, EP_BIAS = 1, EP_GELU = 2, EP_PROJ = 3 };

// ---------------- reductions ----------------
__device__ __forceinline__ float wred_sum(float v) {
#pragma unroll
    for (int o = 32; o >= 1; o >>= 1) v += __shfl_xor(v, o, 64);
    return v;
}
__device__ __forceinline__ float wred_max(float v) {
#pragma unroll
    for (int o = 32; o >= 1; o >>= 1) v = fmaxf(v, __shfl_xor(v, o, 64));
    return v;
}
__device__ __forceinline__ float block_sum_256(float v, float* s4, int tid) {
    v = wred_sum(v);
    __syncthreads();
    if ((tid & 63) == 0) s4[tid >> 6] = v;
    __syncthreads();
    return s4[0] + s4[1] + s4[2] + s4[3];
}
// softmax over 128 logits held as 2 per lane across one 64-lane wave (no barriers)
__device__ __forceinline__ float2 softmax2(float2 l) {
    float m = wred_max(fmaxf(l.x, l.y));
    float e0 = expf(l.x - m), e1 = expf(l.y - m);
    float s = wred_sum(e0 + e1);
    float r = 1.f / s;
    return make_float2(e0 * r, e1 * r);
}

// ---------------- tiled GEMM core ----------------
// C[64x64 tile] = A[:, k0:k0+kLen] @ W[k0:k0+kLen, :].  256 thr, 4x4 micro-tile,
// double-buffered LDS.  EP_PROJ additionally writes row-wise projections
// (row . pw1), (row . pw2) for this block's 64-col head slice.
template<int EPI>
__device__ __forceinline__ void gemm_core(
    const float* __restrict__ A, const float* __restrict__ W,
    const float* __restrict__ bias, float* __restrict__ C,
    int N, int ldA, int k0, int kLen,
    const float* __restrict__ pw1, const float* __restrict__ pw2,
    float* __restrict__ po1, float* __restrict__ po2)
{
    __shared__ float As[2][BK][BM + 4];
    __shared__ float Ws[2][BK][BN];

    const int tid = threadIdx.x;
    const int tx = tid & 15, ty = tid >> 4;
    const int m0 = blockIdx.y * BM;
    const int n0 = blockIdx.x * BN;

    const int a_row = tid >> 2;
    const int a_col = (tid & 3) << 3;
    const float* Aptr = A + (size_t)(m0 + a_row) * ldA + k0 + a_col;
    const int w_row = tid >> 3;
    const int w_col = (tid & 7) << 3;
    const float* Wptr = W + (size_t)(k0 + w_row) * N + n0 + w_col;

    float4 ra0, ra1, rw0, rw1;
    auto fetch = [&](int t) {
        const float* ap = Aptr + t * BK;
        ra0 = *(const float4*)(ap);
        ra1 = *(const float4*)(ap + 4);
        const float* wp = Wptr + (size_t)t * BK * N;
        rw0 = *(const float4*)(wp);
        rw1 = *(const float4*)(wp + 4);
    };
    auto commit = [&](int buf) {
        As[buf][a_col + 0][a_row] = ra0.x;
        As[buf][a_col + 1][a_row] = ra0.y;
        As[buf][a_col + 2][a_row] = ra0.z;
        As[buf][a_col + 3][a_row] = ra0.w;
        As[buf][a_col + 4][a_row] = ra1.x;
        As[buf][a_col + 5][a_row] = ra1.y;
        As[buf][a_col + 6][a_row] = ra1.z;
        As[buf][a_col + 7][a_row] = ra1.w;
        *(float4*)&Ws[buf][w_row][w_col]     = rw0;
        *(float4*)&Ws[buf][w_row][w_col + 4] = rw1;
    };

    float acc[4][4] = {};
    const int ktiles = kLen >> 5;

    fetch(0);
    commit(0);
    __syncthreads();
    for (int t = 0; t < ktiles; ++t) {
        const bool more = (t + 1 < ktiles);
        if (more) fetch(t + 1);
        const int buf = t & 1;
#pragma unroll
        for (int kk = 0; kk < BK; ++kk) {
            float4 a = *(const float4*)&As[buf][kk][ty << 2];
            float4 w = *(const float4*)&Ws[buf][kk][tx << 2];
            acc[0][0] = fmaf(a.x, w.x, acc[0][0]);
            acc[0][1] = fmaf(a.x, w.y, acc[0][1]);
            acc[0][2] = fmaf(a.x, w.z, acc[0][2]);
            acc[0][3] = fmaf(a.x, w.w, acc[0][3]);
            acc[1][0] = fmaf(a.y, w.x, acc[1][0]);
            acc[1][1] = fmaf(a.y, w.y, acc[1][1]);
            acc[1][2] = fmaf(a.y, w.z, acc[1][2]);
            acc[1][3] = fmaf(a.y, w.w, acc[1][3]);
            acc[2][0] = fmaf(a.z, w.x, acc[2][0]);
            acc[2][1] = fmaf(a.z, w.y, acc[2][1]);
            acc[2][2] = fmaf(a.z, w.z, acc[2][2]);
            acc[2][3] = fmaf(a.z, w.w, acc[2][3]);
            acc[3][0] = fmaf(a.w, w.x, acc[3][0]);
            acc[3][1] = fmaf(a.w, w.y, acc[3][1]);
            acc[3][2] = fmaf(a.w, w.z, acc[3][2]);
            acc[3][3] = fmaf(a.w, w.w, acc[3][3]);
        }
        __syncthreads();
        if (more) {
            commit((t + 1) & 1);
            __syncthreads();
        }
    }

    const int row = m0 + (ty << 2);
    const int col = n0 + (tx << 2);
    float4 bv = make_float4(0.f, 0.f, 0.f, 0.f);
    if (EPI != EP_STORE) bv = *(const float4*)&bias[col];
    float4 w1 = make_float4(0.f, 0.f, 0.f, 0.f), w2 = w1;
    if (EPI == EP_PROJ) {
        w1 = *(const float4*)&pw1[tx << 2];
        w2 = *(const float4*)&pw2[tx << 2];
    }
#pragma unroll
    for (int r = 0; r < 4; ++r) {
        float4 o;
        o.x = acc[r][0] + bv.x;
        o.y = acc[r][1] + bv.y;
        o.z = acc[r][2] + bv.z;
        o.w = acc[r][3] + bv.w;
        if (EPI == EP_GELU) {
            o.x = 0.5f * o.x * (1.f + erff(o.x * 0.70710678118654752f));
            o.y = 0.5f * o.y * (1.f + erff(o.y * 0.70710678118654752f));
            o.z = 0.5f * o.z * (1.f + erff(o.z * 0.70710678118654752f));
            o.w = 0.5f * o.w * (1.f + erff(o.w * 0.70710678118654752f));
        }
        *(float4*)&C[(size_t)(row + r) * N + col] = o;
        if (EPI == EP_PROJ) {
            float po = o.x * w1.x + o.y * w1.y + o.z * w1.z + o.w * w1.w;
            float pdd = o.x * w2.x + o.y * w2.y + o.z * w2.z + o.w * w2.w;
#pragma unroll
            for (int off = 1; off < 16; off <<= 1) {
                po  += __shfl_xor(po,  off, 64);
                pdd += __shfl_xor(pdd, off, 64);
            }
            if (tx == 0) {
                int m = row + r;
                int hh = n0 >> 6;
                size_t oidx = ((size_t)(m >> 7) * H_ + hh) * S_ + (m & 127);
                po1[oidx] = po;
                po2[oidx] = pdd;
            }
        }
    }
}

// ---------------- kernel A: compose attack weights ----------------
// z in {0,1}: Wc = W{q,k} @ AW{q,k};  bc = b{q,k} @ AW{q,k} + Ab{q,k}
__global__ __launch_bounds__(256) void compose_kernel(
    const float* __restrict__ Wq, const float* __restrict__ Wk,
    const float* __restrict__ AWq, const float* __restrict__ AWk,
    const float* __restrict__ bq, const float* __restrict__ bk,
    const float* __restrict__ Abq, const float* __restrict__ Abk,
    float* __restrict__ Wcq, float* __restrict__ Wck,
    float* __restrict__ bcq, float* __restrict__ bck)
{
    const int z = blockIdx.z;
    const float* A  = z ? Wk : Wq;
    const float* AW = z ? AWk : AWq;
    if (blockIdx.y < 4) {
        float* C = z ? Wck : Wcq;
        gemm_core<EP_STORE>(A, AW, nullptr, C, HID_, HID_, 0, HID_,
                            nullptr, nullptr, nullptr, nullptr);
    } else {
        __shared__ float red[4][64];
        const float* bsrc = z ? bk : bq;
        const float* Ab   = z ? Abk : Abq;
        float* bco        = z ? bck : bcq;
        int t = threadIdx.x, l = t & 63, kc = t >> 6;
        int n = blockIdx.x * 64 + l;
        float p = 0.f;
#pragma unroll 8
        for (int kk = 0; kk < 64; ++kk) {
            int k = kc * 64 + kk;
            p = fmaf(bsrc[k], AW[(size_t)k * HID_ + n], p);
        }
        red[kc][l] = p;
        __syncthreads();
        if (kc == 0)
            bco[n] = red[0][l] + red[1][l] + red[2][l] + red[3][l] + Ab[n];
    }
}

// ---------------- kernel B: 5 projections of x in one launch ----------------
// z: 0=q (+qo,qd proj), 1=k (+ko,kd proj), 2=v, 3=aq, 4=ak
__global__ __launch_bounds__(256) void xgemm5(
    const float* __restrict__ x,
    const float* __restrict__ Wq, const float* __restrict__ bq,
    const float* __restrict__ Wk, const float* __restrict__ bk,
    const float* __restrict__ Wv, const float* __restrict__ bv,
    const float* __restrict__ Wcq, const float* __restrict__ bcq,
    const float* __restrict__ Wck, const float* __restrict__ bck,
    const float* __restrict__ order_w, const float* __restrict__ dist_w,
    float* __restrict__ q, float* __restrict__ k, float* __restrict__ v,
    float* __restrict__ aq, float* __restrict__ ak,
    float* __restrict__ qoA, float* __restrict__ qdA,
    float* __restrict__ koA, float* __restrict__ kdA)
{
    const int z = blockIdx.z;
    if (z == 0) {
        gemm_core<EP_PROJ>(x, Wq, bq, q, HID_, HID_, 0, HID_,
                           order_w, dist_w, qoA, qdA);
    } else if (z == 1) {
        gemm_core<EP_PROJ>(x, Wk, bk, k, HID_, HID_, 0, HID_,
                           order_w + DH_, dist_w + DH_, koA, kdA);
    } else if (z == 2) {
        gemm_core<EP_BIAS>(x, Wv, bv, v, HID_, HID_, 0, HID_,
                           nullptr, nullptr, nullptr, nullptr);
    } else if (z == 3) {
        gemm_core<EP_BIAS>(x, Wcq, bcq, aq, HID_, HID_, 0, HID_,
                           nullptr, nullptr, nullptr, nullptr);
    } else {
        gemm_core<EP_BIAS>(x, Wck, bck, ak, HID_, HID_, 0, HID_,
                           nullptr, nullptr, nullptr, nullptr);
    }
}

// ---------------- kernel C: batched score GEMMs ----------------
// scores[bh] = qh[bh] @ kh[bh]^T   (and attack variant)
// grid (2,2,64): x=j-tile, y=i-tile, z = type*32 + bh
__global__ __launch_bounds__(256) void score_gemm(
    const float* __restrict__ q, const float* __restrict__ k,
    const float* __restrict__ aq, const float* __restrict__ ak,
    float* __restrict__ scb, float* __restrict__ asb)
{
    __shared__ float As[64][68];   // [d][i]
    __shared__ float Bs[64][68];   // [d][j]
    const int type = blockIdx.z >> 5;
    const int bh = blockIdx.z & 31;
    const int b = bh >> 2, h = bh & 3;
    const float* A  = type ? aq : q;
    const float* Bm = type ? ak : k;
    float* C = type ? asb : scb;

    const int tid = threadIdx.x;
    const int tx = tid & 15, ty = tid >> 4;
    const int m0 = blockIdx.y * 64, n0 = blockIdx.x * 64;

    const int r_ = tid >> 2;            // 0..63
    const int c_ = (tid & 3) << 4;      // 0,16,32,48
    const float* ap = A  + (size_t)(b * S_ + m0 + r_) * HID_ + h * DH_ + c_;
    const float* bp = Bm + (size_t)(b * S_ + n0 + r_) * HID_ + h * DH_ + c_;
#pragma unroll
    for (int u = 0; u < 4; ++u) {
        float4 av = *(const float4*)(ap + u * 4);
        float4 bv = *(const float4*)(bp + u * 4);
        As[c_ + u * 4 + 0][r_] = av.x;
        As[c_ + u * 4 + 1][r_] = av.y;
        As[c_ + u * 4 + 2][r_] = av.z;
        As[c_ + u * 4 + 3][r_] = av.w;
        Bs[c_ + u * 4 + 0][r_] = bv.x;
        Bs[c_ + u * 4 + 1][r_] = bv.y;
        Bs[c_ + u * 4 + 2][r_] = bv.z;
        Bs[c_ + u * 4 + 3][r_] = bv.w;
    }
    __syncthreads();

    float acc[4][4] = {};
#pragma unroll
    for (int kk = 0; kk < 64; ++kk) {
        float4 a = *(const float4*)&As[kk][ty << 2];
        float4 w = *(const float4*)&Bs[kk][tx << 2];
        acc[0][0] = fmaf(a.x, w.x, acc[0][0]);
        acc[0][1] = fmaf(a.x, w.y, acc[0][1]);
        acc[0][2] = fmaf(a.x, w.z, acc[0][2]);
        acc[0][3] = fmaf(a.x, w.w, acc[0][3]);
        acc[1][0] = fmaf(a.y, w.x, acc[1][0]);
        acc[1][1] = fmaf(a.y, w.y, acc[1][1]);
        acc[1][2] = fmaf(a.y, w.z, acc[1][2]);
        acc[1][3] = fmaf(a.y, w.w, acc[1][3]);
        acc[2][0] = fmaf(a.z, w.x, acc[2][0]);
        acc[2][1] = fmaf(a.z, w.y, acc[2][1]);
        acc[2][2] = fmaf(a.z, w.z, acc[2][2]);
        acc[2][3] = fmaf(a.z, w.w, acc[2][3]);
        acc[3][0] = fmaf(a.w, w.x, acc[3][0]);
        acc[3][1] = fmaf(a.w, w.y, acc[3][1]);
        acc[3][2] = fmaf(a.w, w.z, acc[3][2]);
        acc[3][3] = fmaf(a.w, w.w, acc[3][3]);
    }
#pragma unroll
    for (int r = 0; r < 4; ++r) {
        float4 o = make_float4(acc[r][0], acc[r][1], acc[r][2], acc[r][3]);
        *(float4*)&C[((size_t)bh * S_ + m0 + (ty << 2) + r) * S_ + n0 + (tx << 2)] = o;
    }
}

// ---------------- kernel D: 5-softmax chain + PV, one wave per query row ---
// grid 1024 blocks x 256 thr; block = (bh, quad); wave wv handles row quad*4+wv
__global__ __launch_bounds__(256) void softmax_pv(
    const float* __restrict__ scb, const float* __restrict__ asb,
    const float* __restrict__ v,
    const float* __restrict__ qoA, const float* __restrict__ qdA,
    const float* __restrict__ koA, const float* __restrict__ kdA,
    const float* __restrict__ mask,
    const float* __restrict__ order_b_p, const float* __restrict__ dist_b_p,
    const float* __restrict__ scalar_p,
    float* __restrict__ ctx)
{
    const int tid = threadIdx.x;
    const int wv = tid >> 6, lane = tid & 63;
    const int bh = blockIdx.x >> 5;
    const int quad = blockIdx.x & 31;
    const int i = quad * 4 + wv;
    const int b = bh >> 2, h = bh & 3;

    const size_t rowoff = ((size_t)bh * S_ + i) * S_ + 2 * lane;
    float2 sc2 = *(const float2*)&scb[rowoff];
    float2 at2 = *(const float2*)&asb[rowoff];
    float2 mk  = *(const float2*)&mask[((size_t)(b * S_ + i)) * S_ + 2 * lane];
    float2 ko  = *(const float2*)&koA[bh * S_ + 2 * lane];
    float2 kd  = *(const float2*)&kdA[bh * S_ + 2 * lane];
    float qo = qoA[bh * S_ + i];
    float qd = qdA[bh * S_ + i];
    float ob = order_b_p[0], db = dist_b_p[0];
    float scl = scalar_p[0];
    float s2 = scl * scl;
    const float inv = 0.125f;

    float2 rich;
    {
        int j = 2 * lane;
        float pr = 1.f / (1.f + expf(-(qo + ko.x + ob)));
        float sel = (j > i) ? pr : 1.f - pr;
        float erro = logf(sel + 1e-24f);
        float gd = logf(fabsf((float)(j - i)) + 1.f);
        float dd = gd - (qd + kd.x + db);
        rich.x = sc2.x + erro - 0.5f * dd * dd * s2;
    }
    {
        int j = 2 * lane + 1;
        float pr = 1.f / (1.f + expf(-(qo + ko.y + ob)));
        float sel = (j > i) ? pr : 1.f - pr;
        float erro = logf(sel + 1e-24f);
        float gd = logf(fabsf((float)(j - i)) + 1.f);
        float dd = gd - (qd + kd.y + db);
        rich.y = sc2.y + erro - 0.5f * dd * dd * s2;
    }

    float2 p0 = softmax2(make_float2(sc2.x * inv + mk.x, sc2.y * inv + mk.y));
    float2 p1 = softmax2(make_float2(rich.x * inv + mk.x, rich.y * inv + mk.y));
    float2 pc = softmax2(make_float2(p0.x + 0.5f * p1.x, p0.y + 0.5f * p1.y));
    float2 pa = softmax2(make_float2(at2.x * inv + mk.x, at2.y * inv + mk.y));
    float2 pf = softmax2(make_float2(pc.x + 0.5f * pa.x, pc.y + 0.5f * pa.y));

    // PV: ctx[i][d] = sum_j pf[j] * v[j][d], d = lane
    const float* vb = v + (size_t)b * S_ * HID_ + h * DH_ + lane;
    float acc = 0.f;
#pragma unroll 8
    for (int jj = 0; jj < 64; ++jj) {
        float fx = __shfl(pf.x, jj, 64);
        float fy = __shfl(pf.y, jj, 64);
        acc = fmaf(fx, vb[(size_t)(2 * jj) * HID_], acc);
        acc = fmaf(fy, vb[(size_t)(2 * jj + 1) * HID_], acc);
    }
    ctx[((size_t)(b * S_ + i)) * HID_ + h * DH_ + lane] = acc;
}

// ---------------- remaining GEMM wrappers ----------------
__global__ __launch_bounds__(256) void dense_gemm(
    const float* __restrict__ ctx, const float* __restrict__ Wd,
    float* __restrict__ pd0, float* __restrict__ pd1)
{
    const int z = blockIdx.z;
    float* C = z ? pd1 : pd0;
    gemm_core<EP_STORE>(ctx, Wd, nullptr, C, HID_, HID_, z * 128, 128,
                        nullptr, nullptr, nullptr, nullptr);
}

__global__ __launch_bounds__(256) void ff1_gemm(
    const float* __restrict__ h, const float* __restrict__ W1, const float* __restrict__ b1,
    float* __restrict__ f1)
{
    gemm_core<EP_GELU>(h, W1, b1, f1, FF_, HID_, 0, HID_,
                       nullptr, nullptr, nullptr, nullptr);
}

__global__ __launch_bounds__(256) void ff2_gemm(
    const float* __restrict__ f1, const float* __restrict__ W2,
    float* __restrict__ p0, float* __restrict__ p1,
    float* __restrict__ p2, float* __restrict__ p3)
{
    const int z = blockIdx.z;
    float* C = (z == 0) ? p0 : (z == 1) ? p1 : (z == 2) ? p2 : p3;
    gemm_core<EP_STORE>(f1, W2, nullptr, C, HID_, FF_, z * 256, 256,
                        nullptr, nullptr, nullptr, nullptr);
}

// ---------------- LN kernels ----------------
__global__ __launch_bounds__(256) void ln1_kernel(
    const float* __restrict__ pd0, const float* __restrict__ pd1,
    const float* __restrict__ bd, const float* __restrict__ x,
    const float* __restrict__ g1, const float* __restrict__ beta1,
    float* __restrict__ h)
{
    __shared__ float s4[4];
    const int row = blockIdx.x;
    const int n = threadIdx.x;
    const size_t idx = (size_t)row * HID_ + n;
    float val = pd0[idx] + pd1[idx] + bd[n] + x[idx];
    float mean = block_sum_256(val, s4, n) * (1.f / HID_);
    float dv = val - mean;
    float var = block_sum_256(dv * dv, s4, n) * (1.f / HID_);
    h[idx] = dv * rsqrtf(var + 1e-12f) * g1[n] + beta1[n];
}

__global__ __launch_bounds__(256) void ln2_kernel(
    const float* __restrict__ p0, const float* __restrict__ p1,
    const float* __restrict__ p2, const float* __restrict__ p3,
    const float* __restrict__ b2, const float* __restrict__ h,
    const float* __restrict__ g2, const float* __restrict__ beta2,
    float* __restrict__ out)
{
    __shared__ float s4[4];
    const int row = blockIdx.x;
    const int n = threadIdx.x;
    const size_t idx = (size_t)row * HID_ + n;
    float val = p0[idx] + p1[idx] + p2[idx] + p3[idx] + b2[n] + h[idx];
    float mean = block_sum_256(val, s4, n) * (1.f / HID_);
    float dv = val - mean;
    float var = block_sum_256(dv * dv, s4, n) * (1.f / HID_);
    out[idx] = dv * rsqrtf(var + 1e-12f) * g2[n] + beta2[n];
}

// ---------------- launch ----------------
extern "C" void kernel_launch(void* const* d_in, const int* in_sizes, int n_in,
                              void* d_out, int out_size, void* d_ws, size_t ws_size,
                              hipStream_t stream) {
    const float* x        = (const float*)d_in[0];
    const float* mask     = (const float*)d_in[1];
    const float* Wq       = (const float*)d_in[2];
    const float* bq       = (const float*)d_in[3];
    const float* Wk       = (const float*)d_in[4];
    const float* bk       = (const float*)d_in[5];
    const float* Wv       = (const float*)d_in[6];
    const float* bv       = (const float*)d_in[7];
    const float* order_w  = (const float*)d_in[8];
    const float* order_b  = (const float*)d_in[9];
    const float* dist_w   = (const float*)d_in[10];
    const float* dist_b   = (const float*)d_in[11];
    const float* scalar   = (const float*)d_in[12];
    const float* AWq      = (const float*)d_in[13];
    const float* Abq      = (const float*)d_in[14];
    const float* AWk      = (const float*)d_in[15];
    const float* Abk      = (const float*)d_in[16];
    const float* Wd       = (const float*)d_in[17];
    const float* bd       = (const float*)d_in[18];
    const float* g1       = (const float*)d_in[19];
    const float* beta1    = (const float*)d_in[20];
    const float* W1       = (const float*)d_in[21];
    const float* b1       = (const float*)d_in[22];
    const float* W2       = (const float*)d_in[23];
    const float* b2       = (const float*)d_in[24];
    const float* g2       = (const float*)d_in[25];
    const float* beta2    = (const float*)d_in[26];

    const size_t T = (size_t)M_ * HID_;   // 262144 floats
    float* ws   = (float*)d_ws;
    // phase-1 buffers
    float* qb   = ws + 0 * T;
    float* kb   = ws + 1 * T;
    float* vb   = ws + 2 * T;
    float* aqb  = ws + 3 * T;
    float* akb  = ws + 4 * T;
    float* scb  = ws + 5 * T;   // 2T (5,6)
    float* asb  = ws + 7 * T;   // 2T (7,8)
    float* ctxb = ws + 9 * T;
    float* wcb  = ws + 10 * T;  // composed weights + small arrays (<1T)
    float* Wcq = wcb;
    float* Wck = wcb + 65536;
    float* bcq = wcb + 131072;
    float* bck = wcb + 131328;
    float* qoA = wcb + 131584;
    float* qdA = wcb + 135680;
    float* koA = wcb + 139776;
    float* kdA = wcb + 143872;
    // phase-2 reuse (dead after softmax_pv / dense)
    float* pd0 = ws + 0 * T;
    float* pd1 = ws + 1 * T;
    float* hb  = ws + 2 * T;
    float* f1b = ws + 3 * T;    // 4T (3..6)
    float* pf0 = ws + 7 * T;
    float* pf1 = ws + 8 * T;
    float* pf2 = ws + 0 * T;
    float* pf3 = ws + 1 * T;

    compose_kernel<<<dim3(4, 5, 2), 256, 0, stream>>>(
        Wq, Wk, AWq, AWk, bq, bk, Abq, Abk, Wcq, Wck, bcq, bck);
    xgemm5<<<dim3(4, 16, 5), 256, 0, stream>>>(
        x, Wq, bq, Wk, bk, Wv, bv, Wcq, bcq, Wck, bck, order_w, dist_w,
        qb, kb, vb, aqb, akb, qoA, qdA, koA, kdA);
    score_gemm<<<dim3(2, 2, 64), 256, 0, stream>>>(qb, kb, aqb, akb, scb, asb);
    softmax_pv<<<1024, 256, 0, stream>>>(scb, asb, vb, qoA, qdA, koA, kdA,
                                         mask, order_b, dist_b, scalar, ctxb);
    dense_gemm<<<dim3(4, 16, 2), 256, 0, stream>>>(ctxb, Wd, pd0, pd1);
    ln1_kernel<<<M_, 256, 0, stream>>>(pd0, pd1, bd, x, g1, beta1, hb);
    ff1_gemm<<<dim3(16, 16, 1), 256, 0, stream>>>(hb, W1, b1, f1b);
    ff2_gemm<<<dim3(4, 16, 4), 256, 0, stream>>>(f1b, W2, pf0, pf1, pf2, pf3);
    ln2_kernel<<<M_, 256, 0, stream>>>(pf0, pf1, pf2, pf3, b2, hb, g2, beta2, (float*)d_out);
}

// Round 4
// 171.816 us; speedup vs baseline: 1.9210x; 1.1677x over previous
//
#include <hip/hip_runtime.h>
#include <hip/hip_bf16.h>
#include <math.h>

// Problem constants
#define B_  8
#define S_  128
#define HID_ 256
#define H_  4
#define DH_ 64
#define FF_ 1024
#define M_  (B_ * S_)   // 1024 rows

typedef _Float16 half_t;
typedef __attribute__((ext_vector_type(8))) _Float16 half8;
typedef __attribute__((ext_vector_type(4))) float floatx4;

enum { EP_F32 = 0, EP_F16 = 1, EP_F16B = 2, EP_GELU = 3, EP_PROJ = 4 };

__device__ __forceinline__ floatx4 mfma16(half8 a, half8 b, floatx4 c) {
    return __builtin_amdgcn_mfma_f32_16x16x32_f16(a, b, c, 0, 0, 0);
}

// ---------------- reductions ----------------
__device__ __forceinline__ float wred_sum(float v) {
#pragma unroll
    for (int o = 32; o >= 1; o >>= 1) v += __shfl_xor(v, o, 64);
    return v;
}
__device__ __forceinline__ float wred_max(float v) {
#pragma unroll
    for (int o = 32; o >= 1; o >>= 1) v = fmaxf(v, __shfl_xor(v, o, 64));
    return v;
}
__device__ __forceinline__ float block_sum_256(float v, float* s4, int tid) {
    v = wred_sum(v);
    __syncthreads();
    if ((tid & 63) == 0) s4[tid >> 6] = v;
    __syncthreads();
    return s4[0] + s4[1] + s4[2] + s4[3];
}
__device__ __forceinline__ float2 softmax2(float2 l) {
    float m = wred_max(fmaxf(l.x, l.y));
    float e0 = expf(l.x - m), e1 = expf(l.y - m);
    float s = wred_sum(e0 + e1);
    float r = 1.f / s;
    return make_float2(e0 * r, e1 * r);
}

// ---------------- fp16 MFMA GEMM core ----------------
// C[m0:m0+64, n0:n0+64] = A[m0:, :kLen] @ Bt[n0:, :kLen]^T
// A row-major [M x K], Bt row-major [N x K] (i.e. B transposed).
// 256 threads, 4 waves; wave w owns 16-row strip, all 4 col-tiles.
// LDS holds fragments lane-sequentially: Asf[buf][m_tile][lane] is that
// lane's half8 A-fragment (conflict-free b128 reads & writes).
template<int EPI>
__device__ __forceinline__ void mgemm(
    const half_t* __restrict__ A, int ldA,
    const half_t* __restrict__ Bt, int ldB,
    int kLen, int m0, int n0,
    const float* __restrict__ bias,
    float* __restrict__ Cf, half_t* __restrict__ Ch, int ldC,
    const float* __restrict__ pw1, const float* __restrict__ pw2,
    float* __restrict__ po1, float* __restrict__ po2, int hsel)
{
    __shared__ half8 Asf[2][4][64];
    __shared__ half8 Bsf[2][4][64];

    const int tid = threadIdx.x;
    const int w = tid >> 6, l = tid & 63;
    // staging: thread -> one 16B A chunk + one 16B B chunk
    const int sr = tid >> 2;                 // 0..63 (row of A / row of Bt)
    const int sq = tid & 3;                  // k-quad
    const int sdst = (sr & 15) | (sq << 4);  // fragment lane slot
    const int smt = sr >> 4;                 // tile index
    const half_t* Ap = A + (size_t)(m0 + sr) * ldA + sq * 8;
    const half_t* Bp = Bt + (size_t)(n0 + sr) * ldB + sq * 8;

    half8 ra, rb;
    auto fetch = [&](int t) {
        ra = *(const half8*)(Ap + t * 32);
        rb = *(const half8*)(Bp + t * 32);
    };
    auto commit = [&](int buf) {
        Asf[buf][smt][sdst] = ra;
        Bsf[buf][smt][sdst] = rb;
    };

    floatx4 zero = {0.f, 0.f, 0.f, 0.f};
    floatx4 acc[4] = {zero, zero, zero, zero};
    const int kt = kLen >> 5;

    fetch(0);
    commit(0);
    __syncthreads();
    for (int t = 0; t < kt; ++t) {
        const bool more = (t + 1 < kt);
        if (more) fetch(t + 1);
        const int buf = t & 1;
        half8 a = Asf[buf][w][l];
        acc[0] = mfma16(a, Bsf[buf][0][l], acc[0]);
        acc[1] = mfma16(a, Bsf[buf][1][l], acc[1]);
        acc[2] = mfma16(a, Bsf[buf][2][l], acc[2]);
        acc[3] = mfma16(a, Bsf[buf][3][l], acc[3]);
        __syncthreads();
        if (more) {
            commit((t + 1) & 1);
            __syncthreads();
        }
    }

    // epilogue: C/D layout col=lane&15, row=(lane>>4)*4+reg
    const int quad = l >> 4, lc = l & 15;
    const int rowb = m0 + w * 16 + quad * 4;
    float bvv[4] = {0.f, 0.f, 0.f, 0.f};
    if (EPI >= EP_F16B) {
#pragma unroll
        for (int nt = 0; nt < 4; ++nt) bvv[nt] = bias[n0 + nt * 16 + lc];
    }
    float pw1v[4], pw2v[4];
    if (EPI == EP_PROJ) {
#pragma unroll
        for (int nt = 0; nt < 4; ++nt) {
            pw1v[nt] = pw1[nt * 16 + lc];
            pw2v[nt] = pw2[nt * 16 + lc];
        }
    }
#pragma unroll
    for (int rr = 0; rr < 4; ++rr) {
        float ov[4];
#pragma unroll
        for (int nt = 0; nt < 4; ++nt) {
            float o = acc[nt][rr];
            if (EPI >= EP_F16B) o += bvv[nt];
            if (EPI == EP_GELU) o = 0.5f * o * (1.f + erff(o * 0.70710678118654752f));
            ov[nt] = o;
            const size_t ci = (size_t)(rowb + rr) * ldC + n0 + nt * 16 + lc;
            if (EPI == EP_F32) Cf[ci] = o;
            else Ch[ci] = (half_t)o;
        }
        if (EPI == EP_PROJ) {
            float po = ov[0] * pw1v[0] + ov[1] * pw1v[1] + ov[2] * pw1v[2] + ov[3] * pw1v[3];
            float pd = ov[0] * pw2v[0] + ov[1] * pw2v[1] + ov[2] * pw2v[2] + ov[3] * pw2v[3];
#pragma unroll
            for (int off = 1; off < 16; off <<= 1) {
                po += __shfl_xor(po, off, 64);
                pd += __shfl_xor(pd, off, 64);
            }
            if (lc == 0) {
                const int m = rowb + rr;
                const int idx = ((m >> 7) * H_ + hsel) * S_ + (m & 127);
                po1[idx] = po;
                po2[idx] = pd;
            }
        }
    }
}

// ---------------- prep: fp32 -> fp16 converts + transposes ----------------
// z=0: x straight; z=1: Wq straight; z=2: Wk straight;
// z=3..8: transpose 256x256 (Wq,Wk,Wv,Wd,AWq,AWk); z=9: W1^T; z=10: W2^T
__global__ __launch_bounds__(256) void prep_kernel(
    const float* __restrict__ x,
    const float* __restrict__ Wq, const float* __restrict__ Wk,
    const float* __restrict__ Wv, const float* __restrict__ Wd,
    const float* __restrict__ AWq, const float* __restrict__ AWk,
    const float* __restrict__ W1, const float* __restrict__ W2,
    half_t* __restrict__ x16, half_t* __restrict__ Wq16n, half_t* __restrict__ Wk16n,
    half_t* __restrict__ WqT, half_t* __restrict__ WkT, half_t* __restrict__ WvT,
    half_t* __restrict__ WdT, half_t* __restrict__ AWqT, half_t* __restrict__ AWkT,
    half_t* __restrict__ W1T, half_t* __restrict__ W2T)
{
    const int z = blockIdx.z, bx = blockIdx.x, by = blockIdx.y;
    const int tid = threadIdx.x;
    if (z < 3) {
        const float* src = (z == 0) ? x : (z == 1) ? Wq : Wk;
        half_t* dst = (z == 0) ? x16 : (z == 1) ? Wq16n : Wk16n;
        const int total = (z == 0) ? M_ * HID_ : HID_ * HID_;
        const int bid = by * 16 + bx;
        if (bid * 1024 < total) {
            const int base = bid * 1024 + tid * 4;
            float4 vv = *(const float4*)(src + base);
            dst[base + 0] = (half_t)vv.x;
            dst[base + 1] = (half_t)vv.y;
            dst[base + 2] = (half_t)vv.z;
            dst[base + 3] = (half_t)vv.w;
        }
        return;
    }
    // transpose: out[n][k] = in[k][n]
    const float* src; half_t* dst; int K, N, k0, n0;
    if (z <= 8) {
        const float* ins[6] = {Wq, Wk, Wv, Wd, AWq, AWk};
        half_t* outs[6] = {WqT, WkT, WvT, WdT, AWqT, AWkT};
        src = ins[z - 3]; dst = outs[z - 3];
        K = 256; N = 256; k0 = bx * 64; n0 = by * 64;
        if (bx >= 4 || by >= 4) return;
    } else if (z == 9) {
        src = W1; dst = W1T; K = 256; N = 1024;
        k0 = bx * 64; n0 = by * 64;
        if (bx >= 4) return;
    } else {
        src = W2; dst = W2T; K = 1024; N = 256;
        k0 = by * 64; n0 = bx * 64;
        if (bx >= 4) return;
    }
    __shared__ half_t tl[64][72];
    const int r = tid >> 2, c0 = (tid & 3) * 16;
#pragma unroll 4
    for (int i = 0; i < 16; ++i)
        tl[c0 + i][r] = (half_t)src[(size_t)(k0 + r) * N + n0 + c0 + i];
    __syncthreads();
#pragma unroll 4
    for (int i = 0; i < 16; ++i)
        dst[(size_t)(n0 + r) * K + k0 + c0 + i] = tl[r][c0 + i];
}

// ---------------- compose: WcT = AW^T @ W^T (fp16), bc = b@AW + Ab (fp32) --
__global__ __launch_bounds__(256) void compose_mfma(
    const half_t* __restrict__ AWqT, const half_t* __restrict__ AWkT,
    const half_t* __restrict__ Wq16n, const half_t* __restrict__ Wk16n,
    const float* __restrict__ AWq, const float* __restrict__ AWk,
    const float* __restrict__ bq, const float* __restrict__ bk,
    const float* __restrict__ Abq, const float* __restrict__ Abk,
    half_t* __restrict__ WcqT, half_t* __restrict__ WckT,
    float* __restrict__ bcq, float* __restrict__ bck)
{
    const int z = blockIdx.z;
    if (blockIdx.y < 4) {
        const half_t* A = z ? AWkT : AWqT;
        const half_t* Bt = z ? Wk16n : Wq16n;
        half_t* C = z ? WckT : WcqT;
        mgemm<EP_F16>(A, HID_, Bt, HID_, HID_, blockIdx.y * 64, blockIdx.x * 64,
                      nullptr, nullptr, C, HID_, nullptr, nullptr, nullptr, nullptr, 0);
    } else {
        __shared__ float red[4][64];
        const float* bsrc = z ? bk : bq;
        const float* AW   = z ? AWk : AWq;
        const float* Ab   = z ? Abk : Abq;
        float* bco        = z ? bck : bcq;
        int t = threadIdx.x, l = t & 63, kc = t >> 6;
        int n = blockIdx.x * 64 + l;
        float p = 0.f;
#pragma unroll 8
        for (int kk = 0; kk < 64; ++kk) {
            int k = kc * 64 + kk;
            p = fmaf(bsrc[k], AW[(size_t)k * HID_ + n], p);
        }
        red[kc][l] = p;
        __syncthreads();
        if (kc == 0)
            bco[n] = red[0][l] + red[1][l] + red[2][l] + red[3][l] + Ab[n];
    }
}

// ---------------- 5 projections of x in one launch ----------------
__global__ __launch_bounds__(256) void xgemm5(
    const half_t* __restrict__ x16,
    const half_t* __restrict__ WqT, const float* __restrict__ bq,
    const half_t* __restrict__ WkT, const float* __restrict__ bk,
    const half_t* __restrict__ WvT, const float* __restrict__ bv,
    const half_t* __restrict__ WcqT, const float* __restrict__ bcq,
    const half_t* __restrict__ WckT, const float* __restrict__ bck,
    const float* __restrict__ order_w, const float* __restrict__ dist_w,
    half_t* __restrict__ q16, half_t* __restrict__ k16, half_t* __restrict__ v16,
    half_t* __restrict__ aq16, half_t* __restrict__ ak16,
    float* __restrict__ qoA, float* __restrict__ qdA,
    float* __restrict__ koA, float* __restrict__ kdA)
{
    const int z = blockIdx.z;
    const int m0 = blockIdx.y * 64, n0 = blockIdx.x * 64;
    if (z == 0)
        mgemm<EP_PROJ>(x16, HID_, WqT, HID_, HID_, m0, n0, bq, nullptr, q16, HID_,
                       order_w, dist_w, qoA, qdA, blockIdx.x);
    else if (z == 1)
        mgemm<EP_PROJ>(x16, HID_, WkT, HID_, HID_, m0, n0, bk, nullptr, k16, HID_,
                       order_w + DH_, dist_w + DH_, koA, kdA, blockIdx.x);
    else if (z == 2)
        mgemm<EP_F16B>(x16, HID_, WvT, HID_, HID_, m0, n0, bv, nullptr, v16, HID_,
                       nullptr, nullptr, nullptr, nullptr, 0);
    else if (z == 3)
        mgemm<EP_F16B>(x16, HID_, WcqT, HID_, HID_, m0, n0, bcq, nullptr, aq16, HID_,
                       nullptr, nullptr, nullptr, nullptr, 0);
    else
        mgemm<EP_F16B>(x16, HID_, WckT, HID_, HID_, m0, n0, bck, nullptr, ak16, HID_,
                       nullptr, nullptr, nullptr, nullptr, 0);
}

// ---------------- batched score GEMMs (fp32 out) ----------------
__global__ __launch_bounds__(256) void score_mfma(
    const half_t* __restrict__ q16, const half_t* __restrict__ k16,
    const half_t* __restrict__ aq16, const half_t* __restrict__ ak16,
    float* __restrict__ scb, float* __restrict__ asb)
{
    const int type = blockIdx.z >> 5;
    const int bh = blockIdx.z & 31;
    const int b = bh >> 2, h = bh & 3;
    const size_t off = (size_t)b * S_ * HID_ + h * DH_;
    const half_t* A  = (type ? aq16 : q16) + off;
    const half_t* Bt = (type ? ak16 : k16) + off;
    float* C = (type ? asb : scb) + (size_t)bh * S_ * S_;
    mgemm<EP_F32>(A, HID_, Bt, HID_, DH_, blockIdx.y * 64, blockIdx.x * 64,
                  nullptr, C, nullptr, S_, nullptr, nullptr, nullptr, nullptr, 0);
}

// ---------------- 5-softmax chain + PV (one wave per query row) ----------
__global__ __launch_bounds__(256) void softmax_pv(
    const float* __restrict__ scb, const float* __restrict__ asb,
    const half_t* __restrict__ v16,
    const float* __restrict__ qoA, const float* __restrict__ qdA,
    const float* __restrict__ koA, const float* __restrict__ kdA,
    const float* __restrict__ mask,
    const float* __restrict__ order_b_p, const float* __restrict__ dist_b_p,
    const float* __restrict__ scalar_p,
    half_t* __restrict__ ctx16)
{
    const int tid = threadIdx.x;
    const int wv = tid >> 6, lane = tid & 63;
    const int bh = blockIdx.x >> 5;
    const int quad = blockIdx.x & 31;
    const int i = quad * 4 + wv;
    const int b = bh >> 2, h = bh & 3;

    const size_t rowoff = ((size_t)bh * S_ + i) * S_ + 2 * lane;
    float2 sc2 = *(const float2*)&scb[rowoff];
    float2 at2 = *(const float2*)&asb[rowoff];
    float2 mk  = *(const float2*)&mask[((size_t)(b * S_ + i)) * S_ + 2 * lane];
    float2 ko  = *(const float2*)&koA[bh * S_ + 2 * lane];
    float2 kd  = *(const float2*)&kdA[bh * S_ + 2 * lane];
    float qo = qoA[bh * S_ + i];
    float qd = qdA[bh * S_ + i];
    float ob = order_b_p[0], db = dist_b_p[0];
    float scl = scalar_p[0];
    float s2 = scl * scl;
    const float inv = 0.125f;

    float2 rich;
    {
        int j = 2 * lane;
        float pr = 1.f / (1.f + expf(-(qo + ko.x + ob)));
        float sel = (j > i) ? pr : 1.f - pr;
        float erro = logf(sel + 1e-24f);
        float gd = logf(fabsf((float)(j - i)) + 1.f);
        float dd = gd - (qd + kd.x + db);
        rich.x = sc2.x + erro - 0.5f * dd * dd * s2;
    }
    {
        int j = 2 * lane + 1;
        float pr = 1.f / (1.f + expf(-(qo + ko.y + ob)));
        float sel = (j > i) ? pr : 1.f - pr;
        float erro = logf(sel + 1e-24f);
        float gd = logf(fabsf((float)(j - i)) + 1.f);
        float dd = gd - (qd + kd.y + db);
        rich.y = sc2.y + erro - 0.5f * dd * dd * s2;
    }

    float2 p0 = softmax2(make_float2(sc2.x * inv + mk.x, sc2.y * inv + mk.y));
    float2 p1 = softmax2(make_float2(rich.x * inv + mk.x, rich.y * inv + mk.y));
    float2 pc = softmax2(make_float2(p0.x + 0.5f * p1.x, p0.y + 0.5f * p1.y));
    float2 pa = softmax2(make_float2(at2.x * inv + mk.x, at2.y * inv + mk.y));
    float2 pf = softmax2(make_float2(pc.x + 0.5f * pa.x, pc.y + 0.5f * pa.y));

    const half_t* vb = v16 + (size_t)b * S_ * HID_ + h * DH_ + lane;
    float acc = 0.f;
#pragma unroll 8
    for (int jj = 0; jj < 64; ++jj) {
        float fx = __shfl(pf.x, jj, 64);
        float fy = __shfl(pf.y, jj, 64);
        acc = fmaf(fx, (float)vb[(size_t)(2 * jj) * HID_], acc);
        acc = fmaf(fy, (float)vb[(size_t)(2 * jj + 1) * HID_], acc);
    }
    ctx16[((size_t)(b * S_ + i)) * HID_ + h * DH_ + lane] = (half_t)acc;
}

// ---------------- remaining GEMM wrappers ----------------
__global__ __launch_bounds__(256) void dense_mfma(
    const half_t* __restrict__ ctx16, const half_t* __restrict__ WdT,
    float* __restrict__ dn)
{
    mgemm<EP_F32>(ctx16, HID_, WdT, HID_, HID_, blockIdx.y * 64, blockIdx.x * 64,
                  nullptr, dn, nullptr, HID_, nullptr, nullptr, nullptr, nullptr, 0);
}

__global__ __launch_bounds__(256) void ff1_mfma(
    const half_t* __restrict__ h16, const half_t* __restrict__ W1T,
    const float* __restrict__ b1, half_t* __restrict__ f116)
{
    mgemm<EP_GELU>(h16, HID_, W1T, HID_, HID_, blockIdx.y * 64, blockIdx.x * 64,
                   b1, nullptr, f116, FF_, nullptr, nullptr, nullptr, nullptr, 0);
}

__global__ __launch_bounds__(256) void ff2_mfma(
    const half_t* __restrict__ f116, const half_t* __restrict__ W2T,
    float* __restrict__ p0, float* __restrict__ p1)
{
    const int z = blockIdx.z;   // split-K 2 x 512
    float* C = z ? p1 : p0;
    mgemm<EP_F32>(f116 + z * 512, FF_, W2T + z * 512, FF_, 512,
                  blockIdx.y * 64, blockIdx.x * 64,
                  nullptr, C, nullptr, HID_, nullptr, nullptr, nullptr, nullptr, 0);
}

// ---------------- LN kernels ----------------
__global__ __launch_bounds__(256) void ln1_kernel(
    const float* __restrict__ dn, const float* __restrict__ bd,
    const float* __restrict__ x,
    const float* __restrict__ g1, const float* __restrict__ beta1,
    float* __restrict__ h32, half_t* __restrict__ h16)
{
    __shared__ float s4[4];
    const int row = blockIdx.x;
    const int n = threadIdx.x;
    const size_t idx = (size_t)row * HID_ + n;
    float val = dn[idx] + bd[n] + x[idx];
    float mean = block_sum_256(val, s4, n) * (1.f / HID_);
    float dv = val - mean;
    float var = block_sum_256(dv * dv, s4, n) * (1.f / HID_);
    float r = dv * rsqrtf(var + 1e-12f) * g1[n] + beta1[n];
    h32[idx] = r;
    h16[idx] = (half_t)r;
}

__global__ __launch_bounds__(256) void ln2_kernel(
    const float* __restrict__ p0, const float* __restrict__ p1,
    const float* __restrict__ b2, const float* __restrict__ h32,
    const float* __restrict__ g2, const float* __restrict__ beta2,
    float* __restrict__ out)
{
    __shared__ float s4[4];
    const int row = blockIdx.x;
    const int n = threadIdx.x;
    const size_t idx = (size_t)row * HID_ + n;
    float val = p0[idx] + p1[idx] + b2[n] + h32[idx];
    float mean = block_sum_256(val, s4, n) * (1.f / HID_);
    float dv = val - mean;
    float var = block_sum_256(dv * dv, s4, n) * (1.f / HID_);
    out[idx] = dv * rsqrtf(var + 1e-12f) * g2[n] + beta2[n];
}

// ---------------- launch ----------------
extern "C" void kernel_launch(void* const* d_in, const int* in_sizes, int n_in,
                              void* d_out, int out_size, void* d_ws, size_t ws_size,
                              hipStream_t stream) {
    const float* x        = (const float*)d_in[0];
    const float* mask     = (const float*)d_in[1];
    const float* Wq       = (const float*)d_in[2];
    const float* bq       = (const float*)d_in[3];
    const float* Wk       = (const float*)d_in[4];
    const float* bk       = (const float*)d_in[5];
    const float* Wv       = (const float*)d_in[6];
    const float* bv       = (const float*)d_in[7];
    const float* order_w  = (const float*)d_in[8];
    const float* order_b  = (const float*)d_in[9];
    const float* dist_w   = (const float*)d_in[10];
    const float* dist_b   = (const float*)d_in[11];
    const float* scalar   = (const float*)d_in[12];
    const float* AWq      = (const float*)d_in[13];
    const float* Abq      = (const float*)d_in[14];
    const float* AWk      = (const float*)d_in[15];
    const float* Abk      = (const float*)d_in[16];
    const float* Wd       = (const float*)d_in[17];
    const float* bd       = (const float*)d_in[18];
    const float* g1       = (const float*)d_in[19];
    const float* beta1    = (const float*)d_in[20];
    const float* W1       = (const float*)d_in[21];
    const float* b1       = (const float*)d_in[22];
    const float* W2       = (const float*)d_in[23];
    const float* b2       = (const float*)d_in[24];
    const float* g2       = (const float*)d_in[25];
    const float* beta2    = (const float*)d_in[26];

    float* ws = (float*)d_ws;
    size_t off = 0;
    auto afl = [&](size_t n) { float* p = ws + off; off += n; return p; };
    auto ahf = [&](size_t nhalves) { half_t* p = (half_t*)(ws + off); off += nhalves / 2; return p; };

    half_t* x16   = ahf(M_ * HID_);
    half_t* Wq16n = ahf(HID_ * HID_);
    half_t* Wk16n = ahf(HID_ * HID_);
    half_t* WqT   = ahf(HID_ * HID_);
    half_t* WkT   = ahf(HID_ * HID_);
    half_t* WvT   = ahf(HID_ * HID_);
    half_t* WdT   = ahf(HID_ * HID_);
    half_t* AWqT  = ahf(HID_ * HID_);
    half_t* AWkT  = ahf(HID_ * HID_);
    half_t* W1T   = ahf(HID_ * FF_);
    half_t* W2T   = ahf(HID_ * FF_);
    half_t* WcqT  = ahf(HID_ * HID_);
    half_t* WckT  = ahf(HID_ * HID_);
    half_t* q16   = ahf(M_ * HID_);
    half_t* k16   = ahf(M_ * HID_);
    half_t* v16   = ahf(M_ * HID_);
    half_t* aq16  = ahf(M_ * HID_);
    half_t* ak16  = ahf(M_ * HID_);
    half_t* ctx16 = ahf(M_ * HID_);
    half_t* h16   = ahf(M_ * HID_);
    half_t* f116  = ahf(M_ * FF_);
    float* scb  = afl((size_t)B_ * H_ * S_ * S_);
    float* asb  = afl((size_t)B_ * H_ * S_ * S_);
    float* dnb  = afl(M_ * HID_);
    float* hb32 = afl(M_ * HID_);
    float* pf0  = afl(M_ * HID_);
    float* pf1  = afl(M_ * HID_);
    float* bcq  = afl(256);
    float* bck  = afl(256);
    float* qoA  = afl(B_ * H_ * S_);
    float* qdA  = afl(B_ * H_ * S_);
    float* koA  = afl(B_ * H_ * S_);
    float* kdA  = afl(B_ * H_ * S_);

    prep_kernel<<<dim3(16, 16, 11), 256, 0, stream>>>(
        x, Wq, Wk, Wv, Wd, AWq, AWk, W1, W2,
        x16, Wq16n, Wk16n, WqT, WkT, WvT, WdT, AWqT, AWkT, W1T, W2T);
    compose_mfma<<<dim3(4, 5, 2), 256, 0, stream>>>(
        AWqT, AWkT, Wq16n, Wk16n, AWq, AWk, bq, bk, Abq, Abk, WcqT, WckT, bcq, bck);
    xgemm5<<<dim3(4, 16, 5), 256, 0, stream>>>(
        x16, WqT, bq, WkT, bk, WvT, bv, WcqT, bcq, WckT, bck, order_w, dist_w,
        q16, k16, v16, aq16, ak16, qoA, qdA, koA, kdA);
    score_mfma<<<dim3(2, 2, 64), 256, 0, stream>>>(q16, k16, aq16, ak16, scb, asb);
    softmax_pv<<<1024, 256, 0, stream>>>(scb, asb, v16, qoA, qdA, koA, kdA,
                                         mask, order_b, dist_b, scalar, ctx16);
    dense_mfma<<<dim3(4, 16), 256, 0, stream>>>(ctx16, WdT, dnb);
    ln1_kernel<<<M_, 256, 0, stream>>>(dnb, bd, x, g1, beta1, hb32, h16);
    ff1_mfma<<<dim3(16, 16), 256, 0, stream>>>(h16, W1T, b1, f116);
    ff2_mfma<<<dim3(4, 16, 2), 256, 0, stream>>>(f116, W2T, pf0, pf1);
    ln2_kernel<<<M_, 256, 0, stream>>>(pf0, pf1, b2, hb32, g2, beta2, (float*)d_out);
}